// Round 4
// baseline (1565.855 us; speedup 1.0000x reference)
//
#include <hip/hip_runtime.h>
#include <hip/hip_bf16.h>

// Sizes fixed by the reference problem.
#define NN       800000
#define NODE_HD  128
#define MOLR     256
#define IN_DIM   640
#define H1DIM    256
#define H2DIM    128
#define MTILE    64
// x view: per-chunk row = 320 bf16 (640 B exact); h1 view: row = 256 bf16 (512 B exact).
// Both live in one union region; element (row, col) stored at
//   row*ROW + (col ^ ((row&7)<<3))   [short units; (row&7)<<3 = 16B-granular XOR]
// -> balanced bank use for ds_read_b128 (8 lanes per bank-quad = b128 minimum), 16B align kept.

typedef __attribute__((ext_vector_type(4))) float f32x4;
typedef __attribute__((ext_vector_type(4))) short s16x4;
typedef __attribute__((ext_vector_type(8))) short s16x8;

__device__ __forceinline__ short f2bf(float f) {
    union { float f; unsigned u; } v; v.f = f;
    unsigned r = v.u + 0x7fffu + ((v.u >> 16) & 1u);   // round-to-nearest-even
    return (short)(r >> 16);
}

// Pack W1 [640][256] f32 row-major -> bf16 MFMA B-fragment order.
// t = ((kb*16+nb)*64 + lane)*8 + j ; element = W1[kb*32 + (lane>>4)*8 + j][nb*16 + (lane&15)]
__global__ void pack_w1(const float* __restrict__ W1, short* __restrict__ W1p) {
    int t = blockIdx.x * 256 + threadIdx.x;          // < 640*256
    int j = t & 7, l = (t >> 3) & 63, blk = t >> 9;
    int nb = blk & 15, kb = blk >> 4;
    int k = kb * 32 + (l >> 4) * 8 + j;
    int n = nb * 16 + (l & 15);
    W1p[t] = f2bf(W1[k * H1DIM + n]);
}

// Pack W2 [256][128] -> same fragment order (8 n-blocks).
__global__ void pack_w2(const float* __restrict__ W2, short* __restrict__ W2p) {
    int t = blockIdx.x * 256 + threadIdx.x;          // < 256*128
    int j = t & 7, l = (t >> 3) & 63, blk = t >> 9;
    int nb = blk & 7, kb = blk >> 3;
    int k = kb * 32 + (l >> 4) * 8 + j;
    int n = nb * 16 + (l & 15);
    W2p[t] = f2bf(W2[k * H2DIM + n]);
}

__launch_bounds__(256, 3)
__global__ void mlp_fused(const float* __restrict__ nh,
                          const float* __restrict__ c2,
                          const float* __restrict__ tm,
                          const int*   __restrict__ bidx,
                          const short* __restrict__ W1p,
                          const float* __restrict__ b1,
                          const short* __restrict__ W2p,
                          const float* __restrict__ b2,
                          const float* __restrict__ W3,
                          const float* __restrict__ b3,
                          float* __restrict__ out) {
    __shared__ short xh[MTILE * 320];      // 40960 B: x-chunk view (64x320) / h1 view (64x256) union
    __shared__ float b1_lds[H1DIM];
    __shared__ float b2_lds[H2DIM];
    __shared__ float w3_lds[H2DIM];
    __shared__ int   bi_lds[MTILE];
    __shared__ float part_lds[4][MTILE];

    const int tid  = threadIdx.x;
    const int base = blockIdx.x * MTILE;

    if (tid < MTILE) bi_lds[tid] = bidx[base + tid];
    b1_lds[tid] = b1[tid];                              // 256 threads, 256 biases
    if (tid < H2DIM) { b2_lds[tid] = b2[tid]; w3_lds[tid] = W3[tid]; }
    __syncthreads();

    const int l  = tid & 63;
    const int w  = tid >> 6;       // wave id 0..3
    const int lr = l & 15;         // col-in-16 (C/D) / row-in-16 (A)
    const int lh = l >> 4;         // 0..3
    const int axor = (lr & 7) << 3;   // per-lane XOR for A-reads (row&7 == lr&7)

    const f32x4* nh4 = reinterpret_cast<const f32x4*>(nh);
    const f32x4* c24 = reinterpret_cast<const f32x4*>(c2);
    const f32x4* tm4 = reinterpret_cast<const f32x4*>(tm);

    f32x4 acc[4][4] = {};   // layer-1: wave computes 64 rows x 64 cols

    for (int chunk = 0; chunk < 2; ++chunk) {
        // ---- stage 64 x 320 f32 -> bf16 LDS (gather on the fly, swizzled) ----
        #pragma unroll
        for (int i = 0; i < 20; ++i) {
            int idx = tid + i * 256;          // 0..5119
            int row = idx / 80;               // 80 f32x4 per row-chunk
            int q   = idx - row * 80;
            int gc4 = chunk * 80 + q;         // global float4-col 0..159
            int bi  = bi_lds[row];
            f32x4 v;
            if (gc4 < 32)       v = nh4[(size_t)(base + row) * 32 + gc4];
            else if (gc4 < 96)  v = c24[(size_t)bi * 64 + (gc4 - 32)];
            else                v = tm4[(size_t)bi * 64 + (gc4 - 96)];
            s16x4 sv;
            sv[0] = f2bf(v[0]); sv[1] = f2bf(v[1]); sv[2] = f2bf(v[2]); sv[3] = f2bf(v[3]);
            int off = row * 320 + ((q * 4) ^ ((row & 7) << 3));
            *reinterpret_cast<s16x4*>(&xh[off]) = sv;
        }
        __syncthreads();

        // ---- layer-1 MFMA over this K-chunk (10 steps of K=32) ----
        for (int kl = 0; kl < 10; ++kl) {
            const int ks = chunk * 10 + kl;
            s16x8 a[4], bf[4];
            #pragma unroll
            for (int m = 0; m < 4; ++m)
                a[m] = *reinterpret_cast<const s16x8*>(
                          &xh[(m * 16 + lr) * 320 + ((kl * 32 + lh * 8) ^ axor)]);
            #pragma unroll
            for (int n = 0; n < 4; ++n)
                bf[n] = *reinterpret_cast<const s16x8*>(
                          &W1p[(((ks * 16) + (w * 4 + n)) * 64 + l) * 8]);
            #pragma unroll
            for (int m = 0; m < 4; ++m)
                #pragma unroll
                for (int n = 0; n < 4; ++n)
                    acc[m][n] = __builtin_amdgcn_mfma_f32_16x16x32_bf16(
                                    a[m], bf[n], acc[m][n], 0, 0, 0);
        }
        __syncthreads();   // protects xh: next chunk staging / h1 overwrite
    }

    // ---- h1 = relu(acc + b1) -> bf16 into xh (h1 view, swizzled) ----
    #pragma unroll
    for (int m = 0; m < 4; ++m)
        #pragma unroll
        for (int n = 0; n < 4; ++n)
            #pragma unroll
            for (int r = 0; r < 4; ++r) {
                int row = m * 16 + lh * 4 + r;        // C/D: row=(lane>>4)*4+reg
                int col = w * 64 + n * 16 + lr;       //      col=lane&15
                float v = acc[m][n][r] + b1_lds[col];
                xh[row * 256 + (col ^ ((row & 7) << 3))] = f2bf(fmaxf(v, 0.f));
            }
    __syncthreads();

    // ---- layer-2: [64][256] @ [256][128], wave computes 64 x 32 cols ----
    f32x4 acc2[4][2] = {};
    for (int ks = 0; ks < 8; ++ks) {
        s16x8 a[4], bf[2];
        #pragma unroll
        for (int m = 0; m < 4; ++m)
            a[m] = *reinterpret_cast<const s16x8*>(
                      &xh[(m * 16 + lr) * 256 + ((ks * 32 + lh * 8) ^ axor)]);
        #pragma unroll
        for (int n = 0; n < 2; ++n)
            bf[n] = *reinterpret_cast<const s16x8*>(
                      &W2p[((ks * 8 + (w * 2 + n)) * 64 + l) * 8]);
        #pragma unroll
        for (int m = 0; m < 4; ++m)
            #pragma unroll
            for (int n = 0; n < 2; ++n)
                acc2[m][n] = __builtin_amdgcn_mfma_f32_16x16x32_bf16(
                                 a[m], bf[n], acc2[m][n], 0, 0, 0);
    }

    // ---- layer-3: relu(acc2+b2) . W3, reduce across the 16 col-lanes ----
    float part[4][4] = {};   // [m][reg] -> row = m*16 + lh*4 + reg
    #pragma unroll
    for (int m = 0; m < 4; ++m)
        #pragma unroll
        for (int n = 0; n < 2; ++n)
            #pragma unroll
            for (int r = 0; r < 4; ++r) {
                int col = w * 32 + n * 16 + lr;
                float v = fmaxf(acc2[m][n][r] + b2_lds[col], 0.f);
                part[m][r] += v * w3_lds[col];
            }
    #pragma unroll
    for (int mask = 1; mask <= 8; mask <<= 1)
        #pragma unroll
        for (int m = 0; m < 4; ++m)
            #pragma unroll
            for (int r = 0; r < 4; ++r)
                part[m][r] += __shfl_xor(part[m][r], mask, 64);
    if (lr == 0)
        #pragma unroll
        for (int m = 0; m < 4; ++m)
            #pragma unroll
            for (int r = 0; r < 4; ++r)
                part_lds[w][m * 16 + lh * 4 + r] = part[m][r];
    __syncthreads();

    if (tid < MTILE) {
        float logit = part_lds[0][tid] + part_lds[1][tid] +
                      part_lds[2][tid] + part_lds[3][tid] + b3[0];
        out[base + tid] = 1.f / (1.f + __expf(-logit));
    }
}

extern "C" void kernel_launch(void* const* d_in, const int* in_sizes, int n_in,
                              void* d_out, int out_size, void* d_ws, size_t ws_size,
                              hipStream_t stream) {
    (void)in_sizes; (void)n_in; (void)out_size; (void)ws_size;
    const float* nh   = (const float*)d_in[0];
    const float* c2   = (const float*)d_in[1];
    const float* tm   = (const float*)d_in[2];
    const int*   bidx = (const int*)  d_in[3];
    const float* W1   = (const float*)d_in[4];
    const float* b1   = (const float*)d_in[5];
    const float* W2   = (const float*)d_in[6];
    const float* b2   = (const float*)d_in[7];
    const float* W3   = (const float*)d_in[8];
    const float* b3   = (const float*)d_in[9];
    float* out = (float*)d_out;

    short* W1p = (short*)d_ws;                 // 640*256 bf16 = 327,680 B
    short* W2p = W1p + IN_DIM * H1DIM;         // 256*128 bf16 =  65,536 B

    pack_w1<<<dim3((IN_DIM * H1DIM) / 256), dim3(256), 0, stream>>>(W1, W1p);
    pack_w2<<<dim3((H1DIM * H2DIM) / 256), dim3(256), 0, stream>>>(W2, W2p);
    mlp_fused<<<dim3(NN / MTILE), dim3(256), 0, stream>>>(
        nh, c2, tm, bidx, W1p, b1, W2p, b2, W3, b3, out);
}

// Round 5
// 1306.040 us; speedup vs baseline: 1.1989x; 1.1989x over previous
//
#include <hip/hip_runtime.h>
#include <hip/hip_bf16.h>

// Sizes fixed by the reference problem.
#define NN       800000
#define IN_DIM   640
#define H1DIM    256
#define H2DIM    128
#define MTILE    64

typedef __attribute__((ext_vector_type(4))) float f32x4;
typedef __attribute__((ext_vector_type(8))) short s16x8;

__device__ __forceinline__ short f2bf(float f) {
    __hip_bfloat16 h = __float2bfloat16(f);   // RNE; compiler pairs into v_cvt_pk_bf16_f32
    return *reinterpret_cast<short*>(&h);
}

// Pack W1 [640][256] f32 row-major -> bf16 MFMA B-fragment order.
// t = ((kb*16+nb)*64 + lane)*8 + j ; element = W1[kb*32 + (lane>>4)*8 + j][nb*16 + (lane&15)]
__global__ void pack_w1(const float* __restrict__ W1, short* __restrict__ W1p) {
    int t = blockIdx.x * 256 + threadIdx.x;          // < 640*256
    int j = t & 7, l = (t >> 3) & 63, blk = t >> 9;
    int nb = blk & 15, kb = blk >> 4;
    int k = kb * 32 + (l >> 4) * 8 + j;
    int n = nb * 16 + (l & 15);
    W1p[t] = f2bf(W1[k * H1DIM + n]);
}

// Pack W2 [256][128] -> same fragment order (8 n-blocks).
__global__ void pack_w2(const float* __restrict__ W2, short* __restrict__ W2p) {
    int t = blockIdx.x * 256 + threadIdx.x;          // < 256*128
    int j = t & 7, l = (t >> 3) & 63, blk = t >> 9;
    int nb = blk & 7, kb = blk >> 3;
    int k = kb * 32 + (l >> 4) * 8 + j;
    int n = nb * 16 + (l & 15);
    W2p[t] = f2bf(W2[k * H2DIM + n]);
}

// Layer-1 A-fragments are loaded DIRECTLY from global memory by every wave.
// All 4 waves of a block issue identical A addresses -> L1 serves the reuse;
// no x staging, no conversion phase, no barriers in the whole K loop.
__launch_bounds__(256, 2)
__global__ void mlp_fused(const float* __restrict__ nh,
                          const float* __restrict__ c2,
                          const float* __restrict__ tm,
                          const int*   __restrict__ bidx,
                          const short* __restrict__ W1p,
                          const float* __restrict__ b1,
                          const short* __restrict__ W2p,
                          const float* __restrict__ b2,
                          const float* __restrict__ W3,
                          const float* __restrict__ b3,
                          float* __restrict__ out) {
    // h1 tile, XOR-swizzled: element (row,col) at row*256 + (col ^ ((row&7)<<3))
    __shared__ short h1_lds[MTILE * 256];   // 32768 B
    __shared__ float part_lds[4][MTILE];

    const int tid  = threadIdx.x;
    const int base = blockIdx.x * MTILE;
    const int l  = tid & 63;
    const int w  = tid >> 6;
    const int lr = l & 15;
    const int lh = l >> 4;
    const int axor = (lr & 7) << 3;

    // Per-thread A-row base pointers (rows m*16+lr of the tile).
    int bi_m[4];
    #pragma unroll
    for (int m = 0; m < 4; ++m) bi_m[m] = bidx[base + m * 16 + lr];

    f32x4 acc[4][4] = {};   // wave: 64 rows x 64 cols of layer-1 output

    const short* w1base = W1p + ((size_t)(w * 4) * 64 + l) * 8;

    // One K-range: 4 row pointers into a single source, nk K=32 steps,
    // W1 k-block starts at ksBase.
    auto run_ks = [&](const float* r0, const float* r1,
                      const float* r2, const float* r3, int ksBase, int nk) {
        #pragma unroll
        for (int kk = 0; kk < 8; ++kk) {
            if (kk >= nk) break;
            const int off = kk * 32 + lh * 8;
            s16x8 a[4];
            const float* rp0 = r0; const float* rp1 = r1;
            const float* rp2 = r2; const float* rp3 = r3;
            {
                f32x4 u, v; s16x8 t;
                u = *reinterpret_cast<const f32x4*>(rp0 + off);
                v = *reinterpret_cast<const f32x4*>(rp0 + off + 4);
                t[0]=f2bf(u[0]); t[1]=f2bf(u[1]); t[2]=f2bf(u[2]); t[3]=f2bf(u[3]);
                t[4]=f2bf(v[0]); t[5]=f2bf(v[1]); t[6]=f2bf(v[2]); t[7]=f2bf(v[3]);
                a[0] = t;
                u = *reinterpret_cast<const f32x4*>(rp1 + off);
                v = *reinterpret_cast<const f32x4*>(rp1 + off + 4);
                t[0]=f2bf(u[0]); t[1]=f2bf(u[1]); t[2]=f2bf(u[2]); t[3]=f2bf(u[3]);
                t[4]=f2bf(v[0]); t[5]=f2bf(v[1]); t[6]=f2bf(v[2]); t[7]=f2bf(v[3]);
                a[1] = t;
                u = *reinterpret_cast<const f32x4*>(rp2 + off);
                v = *reinterpret_cast<const f32x4*>(rp2 + off + 4);
                t[0]=f2bf(u[0]); t[1]=f2bf(u[1]); t[2]=f2bf(u[2]); t[3]=f2bf(u[3]);
                t[4]=f2bf(v[0]); t[5]=f2bf(v[1]); t[6]=f2bf(v[2]); t[7]=f2bf(v[3]);
                a[2] = t;
                u = *reinterpret_cast<const f32x4*>(rp3 + off);
                v = *reinterpret_cast<const f32x4*>(rp3 + off + 4);
                t[0]=f2bf(u[0]); t[1]=f2bf(u[1]); t[2]=f2bf(u[2]); t[3]=f2bf(u[3]);
                t[4]=f2bf(v[0]); t[5]=f2bf(v[1]); t[6]=f2bf(v[2]); t[7]=f2bf(v[3]);
                a[3] = t;
            }
            const int ks = ksBase + kk;
            s16x8 bfr[4];
            #pragma unroll
            for (int n = 0; n < 4; ++n)
                bfr[n] = *reinterpret_cast<const s16x8*>(
                            w1base + ((size_t)ks * 16 + n) * 64 * 8);
            #pragma unroll
            for (int m = 0; m < 4; ++m)
                #pragma unroll
                for (int n = 0; n < 4; ++n)
                    acc[m][n] = __builtin_amdgcn_mfma_f32_16x16x32_bf16(
                                    a[m], bfr[n], acc[m][n], 0, 0, 0);
        }
    };

    run_ks(nh + (size_t)(base + 0 * 16 + lr) * 128,
           nh + (size_t)(base + 1 * 16 + lr) * 128,
           nh + (size_t)(base + 2 * 16 + lr) * 128,
           nh + (size_t)(base + 3 * 16 + lr) * 128, 0, 4);
    run_ks(c2 + (size_t)bi_m[0] * 256, c2 + (size_t)bi_m[1] * 256,
           c2 + (size_t)bi_m[2] * 256, c2 + (size_t)bi_m[3] * 256, 4, 8);
    run_ks(tm + (size_t)bi_m[0] * 256, tm + (size_t)bi_m[1] * 256,
           tm + (size_t)bi_m[2] * 256, tm + (size_t)bi_m[3] * 256, 12, 8);

    // ---- h1 = relu(acc + b1) -> bf16 LDS (swizzled) ----
    float b1c[4];
    #pragma unroll
    for (int n = 0; n < 4; ++n) b1c[n] = b1[w * 64 + n * 16 + lr];
    #pragma unroll
    for (int m = 0; m < 4; ++m)
        #pragma unroll
        for (int n = 0; n < 4; ++n)
            #pragma unroll
            for (int r = 0; r < 4; ++r) {
                int row = m * 16 + lh * 4 + r;        // C/D: row=(lane>>4)*4+reg
                int col = w * 64 + n * 16 + lr;       //      col=lane&15
                float v = acc[m][n][r] + b1c[n];
                h1_lds[row * 256 + (col ^ ((row & 7) << 3))] = f2bf(fmaxf(v, 0.f));
            }
    __syncthreads();

    // ---- layer-2: [64][256] @ [256][128], wave computes 64 x 32 cols ----
    f32x4 acc2[4][2] = {};
    const short* w2base = W2p + ((size_t)(w * 2) * 64 + l) * 8;
    #pragma unroll
    for (int ks = 0; ks < 8; ++ks) {
        s16x8 a[4], bfr[2];
        #pragma unroll
        for (int m = 0; m < 4; ++m)
            a[m] = *reinterpret_cast<const s16x8*>(
                      &h1_lds[(m * 16 + lr) * 256 + ((ks * 32 + lh * 8) ^ axor)]);
        #pragma unroll
        for (int n = 0; n < 2; ++n)
            bfr[n] = *reinterpret_cast<const s16x8*>(
                        w2base + ((size_t)ks * 8 + n) * 64 * 8);
        #pragma unroll
        for (int m = 0; m < 4; ++m)
            #pragma unroll
            for (int n = 0; n < 2; ++n)
                acc2[m][n] = __builtin_amdgcn_mfma_f32_16x16x32_bf16(
                                 a[m], bfr[n], acc2[m][n], 0, 0, 0);
    }

    // ---- layer-3: relu(acc2+b2) . W3, reduce across the 16 col-lanes ----
    float b2c[2], w3c[2];
    #pragma unroll
    for (int n = 0; n < 2; ++n) {
        b2c[n] = b2[w * 32 + n * 16 + lr];
        w3c[n] = W3[w * 32 + n * 16 + lr];
    }
    float part[4][4] = {};   // [m][reg] -> row = m*16 + lh*4 + reg
    #pragma unroll
    for (int m = 0; m < 4; ++m)
        #pragma unroll
        for (int n = 0; n < 2; ++n)
            #pragma unroll
            for (int r = 0; r < 4; ++r) {
                float v = fmaxf(acc2[m][n][r] + b2c[n], 0.f);
                part[m][r] += v * w3c[n];
            }
    #pragma unroll
    for (int mask = 1; mask <= 8; mask <<= 1)
        #pragma unroll
        for (int m = 0; m < 4; ++m)
            #pragma unroll
            for (int r = 0; r < 4; ++r)
                part[m][r] += __shfl_xor(part[m][r], mask, 64);
    if (lr == 0)
        #pragma unroll
        for (int m = 0; m < 4; ++m)
            #pragma unroll
            for (int r = 0; r < 4; ++r)
                part_lds[w][m * 16 + lh * 4 + r] = part[m][r];
    __syncthreads();

    if (tid < MTILE) {
        float logit = part_lds[0][tid] + part_lds[1][tid] +
                      part_lds[2][tid] + part_lds[3][tid] + b3[0];
        out[base + tid] = 1.f / (1.f + __expf(-logit));
    }
}

extern "C" void kernel_launch(void* const* d_in, const int* in_sizes, int n_in,
                              void* d_out, int out_size, void* d_ws, size_t ws_size,
                              hipStream_t stream) {
    (void)in_sizes; (void)n_in; (void)out_size; (void)ws_size;
    const float* nh   = (const float*)d_in[0];
    const float* c2   = (const float*)d_in[1];
    const float* tm   = (const float*)d_in[2];
    const int*   bidx = (const int*)  d_in[3];
    const float* W1   = (const float*)d_in[4];
    const float* b1   = (const float*)d_in[5];
    const float* W2   = (const float*)d_in[6];
    const float* b2   = (const float*)d_in[7];
    const float* W3   = (const float*)d_in[8];
    const float* b3   = (const float*)d_in[9];
    float* out = (float*)d_out;

    short* W1p = (short*)d_ws;                 // 640*256 bf16 = 327,680 B
    short* W2p = W1p + IN_DIM * H1DIM;         // 256*128 bf16 =  65,536 B

    pack_w1<<<dim3((IN_DIM * H1DIM) / 256), dim3(256), 0, stream>>>(W1, W1p);
    pack_w2<<<dim3((H1DIM * H2DIM) / 256), dim3(256), 0, stream>>>(W2, W2p);
    mlp_fused<<<dim3(NN / MTILE), dim3(256), 0, stream>>>(
        nh, c2, tm, bidx, W1p, b1, W2p, b2, W3, b3, out);
}